// Round 6
// baseline (64.687 us; speedup 1.0000x reference)
//
#include <hip/hip_runtime.h>
#include <math.h>

// Problem constants (from reference)
#define MEMN 8
#define WDIM 41      // 1 + DEG*MEM = 1 + 5*8
#define BB   32
#define LL   4096
#define PADN 15      // 2*MEM - 1
#define TILE_T 4     // t-values per block
#define WIN 18       // TILE_T - 1 + PADN  window length per b
#define STRIDE 19    // odd LDS stride (dwords) -> conflict-free over b

// out[b,t,:] = co[t] broadcast;  co[t] = sum_b sum_m xp[b,t+m] * acc_m
// where acc_m = W[m,0] + sum_mm ( W[m,1+5mm]*xp[b,t+m+mm]
//                + W[m,2+5mm] + W[m,3+5mm]*a + W[m,4+5mm]*a^2 + W[m,5+5mm]*a^3 )
// xp[b,j] = x[b, j-15] (zeros for j<15), a = |xp[b, t+m+mm]|.
//
// Thread = (b, t-slot, mq); mq in [0,4) owns m in {2mq, 2mq+1}.
// 512 threads/block, 1024 blocks -> 8192 waves = 8 waves/SIMD.
// R4 established: readfirstlane(m) -> uniform W pointers -> s_load (no spill).
//
// ROUND-5: two VALU cuts, VGPR-neutral:
//  (1) fold[m] = W[m,0] + sum_mm W[m,2+5mm] is data-independent -> computed
//      once per block into LDS by 16 staging lanes; accumulators init from it
//      (-32 VALU/thread, -32 s_loads).
//  (2) k-loop restructure (k = ml+mm): v^2,v^3 computed 9x not 16x, and both
//      m-rows' accumulator chains live together (-14 VALU, 2x chain ILP).

__global__ __launch_bounds__(512, 8)
void gmp_kernel(const float* __restrict__ x,   // (B, L, 2)
                const float* __restrict__ Wr,  // (MEM, WDIM)
                const float* __restrict__ Wi,  // (MEM, WDIM)
                float* __restrict__ out)       // (B, L, 2)
{
    __shared__ float s_re[BB * STRIDE];
    __shared__ float s_im[BB * STRIDE];
    __shared__ float s_am[BB * STRIDE];
    __shared__ float s_wc[MEMN][2];          // folded constant term per m (re/im)
    __shared__ float s_part[TILE_T][4][2];   // [t-slot][mq][re/im]

    const int tid = threadIdx.x;
    const int t0  = blockIdx.x * TILE_T;

    // ---- stage x window into LDS: s_*[b*STRIDE + o] = xp[b, t0 + o], o in [0,WIN) ----
    {
        const int o  = tid & 31;   // only o < WIN active
        const int b8 = tid >> 5;   // 0..15
        if (o < WIN) {
            const int g = t0 - PADN + o;   // global t-index into x (max 4094 < LL)
            #pragma unroll
            for (int it = 0; it < 2; ++it) {
                const int b = b8 + 16 * it;
                float re = 0.f, im = 0.f;
                if (g >= 0) {
                    const float2 v = *(const float2*)(x + ((size_t)b * LL + g) * 2);
                    re = v.x; im = v.y;
                }
                s_re[b * STRIDE + o] = re;
                s_im[b * STRIDE + o] = im;
                s_am[b * STRIDE + o] = sqrtf(re * re + im * im);
            }
        }
    }
    // ---- fold the data-independent channel: s_wc[m][c] = W[m,0] + sum_mm W[m,2+5mm] ----
    if (tid < 2 * MEMN) {
        const int m = tid >> 1, c = tid & 1;
        const float* __restrict__ W = c ? Wi : Wr;
        float v = W[m * WDIM];
        #pragma unroll
        for (int mm = 0; mm < MEMN; ++mm) v += W[m * WDIM + 2 + 5 * mm];
        s_wc[m][c] = v;
    }
    __syncthreads();

    // ---- compute: thread = (b, t-slot, mq) ----
    const int b    = tid & 31;
    const int slot = (tid >> 5) & 3;
    const int mq   = tid >> 7;             // constant across each 64-lane wave
    const int base = b * STRIDE + slot + 2 * mq;

    // x-window registers: k = ml + mm in [0, 8]  (27 VGPRs)
    float zr[9], zi[9], a1[9];
    #pragma unroll
    for (int k = 0; k < 9; ++k) {
        zr[k] = s_re[base + k];
        zi[k] = s_im[base + k];
        a1[k] = s_am[base + k];
    }

    // Uniform W row pointers (SGPR) for m0 = 2mq, m1 = 2mq+1.
    const int m0 = __builtin_amdgcn_readfirstlane(2 * mq);
    const float* __restrict__ Wr0 = Wr + m0 * WDIM;
    const float* __restrict__ Wi0 = Wi + m0 * WDIM;
    const float* __restrict__ Wr1 = Wr0 + WDIM;
    const float* __restrict__ Wi1 = Wi0 + WDIM;

    float ar0 = s_wc[m0][0],     ai0 = s_wc[m0][1];      // broadcast ds_read
    float ar1 = s_wc[m0 + 1][0], ai1 = s_wc[m0 + 1][1];

    // k-loop: row m0 uses mm=k (k<8), row m1 uses mm=k-1 (k>0); v1/v2/v3 shared.
    #pragma unroll
    for (int k = 0; k < 9; ++k) {
        const float v1 = a1[k];
        const float v2 = v1 * v1;
        const float v3 = v2 * v1;
        const float xr = zr[k];
        const float xi = zi[k];
        if (k < 8) {
            const int wb = 1 + 5 * k;           // coeff base in row m0
            const float w0r = Wr0[wb], w0i = Wi0[wb];
            ar0 += w0r * xr - w0i * xi;
            ai0 += w0r * xi + w0i * xr;
            ar0 += Wr0[wb + 2] * v1 + Wr0[wb + 3] * v2 + Wr0[wb + 4] * v3;
            ai0 += Wi0[wb + 2] * v1 + Wi0[wb + 3] * v2 + Wi0[wb + 4] * v3;
        }
        if (k > 0) {
            const int wb = 1 + 5 * (k - 1);     // coeff base in row m1
            const float w0r = Wr1[wb], w0i = Wi1[wb];
            ar1 += w0r * xr - w0i * xi;
            ai1 += w0r * xi + w0i * xr;
            ar1 += Wr1[wb + 2] * v1 + Wr1[wb + 3] * v2 + Wr1[wb + 4] * v3;
            ai1 += Wi1[wb + 2] * v1 + Wi1[wb + 3] * v2 + Wi1[wb + 4] * v3;
        }
    }

    // contrib: z[b,t+m0] is window index 0, z[b,t+m1] is window index 1
    float cr = zr[0] * ar0 - zi[0] * ai0 + zr[1] * ar1 - zi[1] * ai1;
    float ci = zr[0] * ai0 + zi[0] * ar0 + zr[1] * ai1 + zi[1] * ar1;

    // ---- butterfly reduce over b (32-lane halves of each wave) ----
    #pragma unroll
    for (int mask = 16; mask >= 1; mask >>= 1) {
        cr += __shfl_xor(cr, mask, 64);
        ci += __shfl_xor(ci, mask, 64);
    }
    if (b == 0) {
        s_part[slot][mq][0] = cr;
        s_part[slot][mq][1] = ci;
    }
    __syncthreads();

    // ---- combine mq partials + broadcast write: out[b'][t0+j][:] ----
    if (tid < BB * TILE_T) {
        const int j  = tid & (TILE_T - 1);  // 0..3
        const int bw = tid >> 2;            // 0..31
        float2 v;
        v.x = s_part[j][0][0] + s_part[j][1][0] + s_part[j][2][0] + s_part[j][3][0];
        v.y = s_part[j][0][1] + s_part[j][1][1] + s_part[j][2][1] + s_part[j][3][1];
        *(float2*)(out + ((size_t)bw * LL + t0 + j) * 2) = v;
    }
}

extern "C" void kernel_launch(void* const* d_in, const int* in_sizes, int n_in,
                              void* d_out, int out_size, void* d_ws, size_t ws_size,
                              hipStream_t stream) {
    const float* x  = (const float*)d_in[0];
    // d_in[1] = h_0 : unused by the reference computation
    const float* Wr = (const float*)d_in[2];
    const float* Wi = (const float*)d_in[3];
    float* out = (float*)d_out;

    gmp_kernel<<<dim3(LL / TILE_T), dim3(512), 0, stream>>>(x, Wr, Wi, out);
}